// Round 1
// baseline (1070.806 us; speedup 1.0000x reference)
//
#include <hip/hip_runtime.h>
#include <math.h>

// Router: logits = X[32768,2048] @ W[64,2048]^T ; softmax over 64; top-8 (stable).
// Outputs (all written as float into one flat buffer):
//   [0]  probs   : N*64
//   [1]  top val : N*8
//   [2]  top idx : N*8   (written as float(index); harness reads whole buffer as f32)

constexpr int HD  = 2048;   // hidden dim
constexpr int NE  = 64;     // experts
constexpr int RPB = 64;     // rows per block (lane == row)
constexpr int NW  = 4;      // waves per block (split D)
constexpr int DSL = HD / NW;   // 512 per wave
constexpr int CH  = 16;        // d-chunk per inner pass (precision chunking + 16 SGPR weight regs)
constexpr int NCH = DSL / CH;  // 32 chunks
constexpr int TOPK = 8;

__global__ __launch_bounds__(256, 2)
void router_k(const float* __restrict__ X, const float* __restrict__ W,
              float* __restrict__ probs, float* __restrict__ topv,
              float* __restrict__ topi) {
  // padded stride 65 -> bank = (lane+e)%32, conflict-free writes/reads
  __shared__ float buf[2][RPB][NE + 1];

  const int tid  = threadIdx.x;
  const int wv   = tid >> 6;
  const int lane = tid & 63;
  const long rowbase = (long)blockIdx.x * RPB;
  const long row = rowbase + lane;

  const float* xp = X + row * (long)HD + wv * DSL;
  // force wave-uniform weight base so the compiler emits scalar (SMEM) loads
  const int woff = __builtin_amdgcn_readfirstlane(wv * DSL);
  const float* wp = W + woff;

  float acc[NE];
#pragma unroll
  for (int e = 0; e < NE; ++e) acc[e] = 0.f;

  auto load_chunk = [&](float (&x)[CH], int c) {
#pragma unroll
    for (int j = 0; j < CH; j += 4) {
      const float4 t = *reinterpret_cast<const float4*>(xp + c * CH + j);
      x[j] = t.x; x[j + 1] = t.y; x[j + 2] = t.z; x[j + 3] = t.w;
    }
  };
  auto compute_chunk = [&](const float (&x)[CH], int c) {
    const float* wc = wp + c * CH;
#pragma unroll
    for (int e = 0; e < NE; ++e) {
      float psum = 0.f;   // short 16-term chain keeps rounding error ~1e-8
#pragma unroll
      for (int j = 0; j < CH; ++j)
        psum = fmaf(x[j], wc[(long)e * HD + j], psum);
      acc[e] += psum;
    }
  };

  // double-buffered x regs: loads of next chunk fly over fmacs of current
  float xa[CH], xb[CH];
  load_chunk(xa, 0);
  for (int c = 0; c < NCH; c += 2) {
    load_chunk(xb, c + 1);
    compute_chunk(xa, c);
    if (c + 2 < NCH) load_chunk(xa, c + 2);
    compute_chunk(xb, c + 1);
  }

  // ---- cross-wave reduction (paired, <=33KB LDS) ----
  if (wv >= 2) {
#pragma unroll
    for (int e = 0; e < NE; ++e) buf[wv - 2][lane][e] = acc[e];
  }
  __syncthreads();
  if (wv < 2) {
#pragma unroll
    for (int e = 0; e < NE; ++e) acc[e] += buf[wv][lane][e];
  }
  __syncthreads();
  if (wv == 1) {
#pragma unroll
    for (int e = 0; e < NE; ++e) buf[0][lane][e] = acc[e];
  }
  __syncthreads();
  if (wv == 0) {
#pragma unroll
    for (int e = 0; e < NE; ++e) buf[1][lane][e] = acc[e] + buf[0][lane][e];
  }
  __syncthreads();

  // ---- epilogue: softmax + stable top-8, 16 rows per wave, lane == expert ----
  for (int rr = 0; rr < RPB / NW; ++rr) {
    const int r = wv * (RPB / NW) + rr;
    const float lg = buf[1][r][lane];

    float m = lg;
#pragma unroll
    for (int off = 32; off; off >>= 1)
      m = fmaxf(m, __shfl_xor(m, off, 64));

    const float ex = expf(lg - m);
    float s = ex;
#pragma unroll
    for (int off = 32; off; off >>= 1)
      s += __shfl_xor(s, off, 64);

    const float p = ex * (1.0f / s);
    probs[(rowbase + r) * NE + lane] = p;

    // stable rank: #(p_j > p) + #(p_j == p with j < lane)  -> matches lax.top_k ties
    int rank = 0;
#pragma unroll
    for (int j = 0; j < NE; ++j) {
      const float pj = __shfl(p, j, 64);
      rank += (pj > p) || (pj == p && j < lane);
    }
    if (rank < TOPK) {
      topv[(rowbase + r) * TOPK + rank] = p;
      topi[(rowbase + r) * TOPK + rank] = (float)lane;
    }
  }
}

extern "C" void kernel_launch(void* const* d_in, const int* in_sizes, int n_in,
                              void* d_out, int out_size, void* d_ws, size_t ws_size,
                              hipStream_t stream) {
  const float* X = (const float*)d_in[0];
  const float* W = (const float*)d_in[1];
  const int n = in_sizes[0] / HD;          // 32768 tokens

  float* probs = (float*)d_out;
  float* topv  = probs + (size_t)n * NE;
  float* topi  = topv + (size_t)n * TOPK;

  dim3 grid(n / RPB), block(256);
  hipLaunchKernelGGL(router_k, grid, block, 0, stream, X, W, probs, topv, topi);
}

// Round 2
// 810.014 us; speedup vs baseline: 1.3220x; 1.3220x over previous
//
#include <hip/hip_runtime.h>
#include <math.h>

// Router: logits = X[32768,2048] @ W[64,2048]^T ; softmax over 64; top-8 (stable).
// Structure: 512 blocks x 4 waves. Block owns 64 rows; wave owns a 512-wide d-slice.
// Lane grid within wave: r0 = lane>>3 (8 rows), e0 = lane&7 (8 experts).
// Thread computes an 8x8 register outer-product tile: rows r0+8i, experts e0+8j.
// Main loop is pure VALU + per-lane global vector loads (x reused x8 across experts,
// w reused x8 across rows, w is L2-resident). No LDS/barriers/scalar loads in loop.
// Chunk-16 partial sums (ps) keep accumulation error ~1e-7 so top-8 indices match
// the numpy fp32 reference exactly (index threshold is effectively exact-match).

constexpr int HD   = 2048;
constexpr int NE   = 64;
constexpr int RPB  = 64;    // rows per block
constexpr int TOPK = 8;
constexpr int DSL  = 512;   // d-slice per wave (4 waves cover 2048)
constexpr int NCH  = 32;    // chunks of 16d per slice

__global__ __launch_bounds__(256, 2)
void router_k(const float* __restrict__ X, const float* __restrict__ W,
              float* __restrict__ probs, float* __restrict__ topv,
              float* __restrict__ topi) {
  __shared__ float red[2][RPB][NE + 1];   // 33,280 B; stride 65 -> 2-way banks (free)

  const int tid  = threadIdx.x;
  const int wv   = tid >> 6;
  const int lane = tid & 63;
  const int r0   = lane >> 3;   // row sub-index
  const int e0   = lane & 7;    // expert sub-index
  const int rowbase = blockIdx.x * RPB;

  const float* xb = X + (size_t)(rowbase + r0) * HD + wv * DSL;
  const float* wb = W + (size_t)e0 * HD + wv * DSL;

  float acc[8][8];
#pragma unroll
  for (int i = 0; i < 8; ++i)
#pragma unroll
    for (int j = 0; j < 8; ++j) acc[i][j] = 0.f;

  for (int c = 0; c < NCH; ++c) {
    float ps[8][8];
#pragma unroll
    for (int q = 0; q < 4; ++q) {
      float4 xq[8], wq[8];
#pragma unroll
      for (int i = 0; i < 8; ++i)
        xq[i] = *reinterpret_cast<const float4*>(xb + (size_t)i * 8 * HD + c * 16 + q * 4);
#pragma unroll
      for (int j = 0; j < 8; ++j)
        wq[j] = *reinterpret_cast<const float4*>(wb + (size_t)j * 8 * HD + c * 16 + q * 4);
#pragma unroll
      for (int i = 0; i < 8; ++i)
#pragma unroll
        for (int j = 0; j < 8; ++j) {
          float t = (q == 0) ? (xq[i].x * wq[j].x)
                             : fmaf(xq[i].x, wq[j].x, ps[i][j]);
          t = fmaf(xq[i].y, wq[j].y, t);
          t = fmaf(xq[i].z, wq[j].z, t);
          t = fmaf(xq[i].w, wq[j].w, t);
          ps[i][j] = t;
        }
    }
#pragma unroll
    for (int i = 0; i < 8; ++i)
#pragma unroll
      for (int j = 0; j < 8; ++j) acc[i][j] += ps[i][j];
  }

  // ---- cross-wave (d-split) tree reduction: (w0+w2) + (w1+w3) ----
  if (wv >= 2) {
#pragma unroll
    for (int i = 0; i < 8; ++i)
#pragma unroll
      for (int j = 0; j < 8; ++j)
        red[wv - 2][r0 + 8 * i][e0 + 8 * j] = acc[i][j];
  }
  __syncthreads();
  if (wv < 2) {
#pragma unroll
    for (int i = 0; i < 8; ++i)
#pragma unroll
      for (int j = 0; j < 8; ++j)
        acc[i][j] += red[wv][r0 + 8 * i][e0 + 8 * j];
  }
  __syncthreads();
  if (wv == 1) {
#pragma unroll
    for (int i = 0; i < 8; ++i)
#pragma unroll
      for (int j = 0; j < 8; ++j)
        red[0][r0 + 8 * i][e0 + 8 * j] = acc[i][j];
  }
  __syncthreads();
  if (wv == 0) {
#pragma unroll
    for (int i = 0; i < 8; ++i)
#pragma unroll
      for (int j = 0; j < 8; ++j)
        red[1][r0 + 8 * i][e0 + 8 * j] = acc[i][j] + red[0][r0 + 8 * i][e0 + 8 * j];
  }
  __syncthreads();

  // ---- epilogue: softmax + stable top-8; 16 rows per wave, lane == expert ----
  for (int k = 0; k < RPB / 4; ++k) {
    const int rr = wv * (RPB / 4) + k;
    const float lg = red[1][rr][lane];

    float m = lg;
#pragma unroll
    for (int off = 32; off; off >>= 1)
      m = fmaxf(m, __shfl_xor(m, off, 64));

    const float ex = expf(lg - m);
    float s = ex;
#pragma unroll
    for (int off = 32; off; off >>= 1)
      s += __shfl_xor(s, off, 64);

    const float p = ex * (1.0f / s);
    probs[(size_t)(rowbase + rr) * NE + lane] = p;

    // stable rank: #(p_j > p) + #(p_j == p with j < lane) -> matches lax.top_k ties
    int rank = 0;
#pragma unroll
    for (int j = 0; j < NE; ++j) {
      const float pj = __shfl(p, j, 64);
      rank += (pj > p) || (pj == p && j < lane);
    }
    if (rank < TOPK) {
      topv[(size_t)(rowbase + rr) * TOPK + rank] = p;
      topi[(size_t)(rowbase + rr) * TOPK + rank] = (float)lane;
    }
  }
}

extern "C" void kernel_launch(void* const* d_in, const int* in_sizes, int n_in,
                              void* d_out, int out_size, void* d_ws, size_t ws_size,
                              hipStream_t stream) {
  const float* X = (const float*)d_in[0];
  const float* W = (const float*)d_in[1];
  const int n = in_sizes[0] / HD;          // 32768 tokens

  float* probs = (float*)d_out;
  float* topv  = probs + (size_t)n * NE;
  float* topi  = topv + (size_t)n * TOPK;

  dim3 grid(n / RPB), block(256);
  hipLaunchKernelGGL(router_k, grid, block, 0, stream, X, W, probs, topv, topi);
}